// Round 5
// baseline (511.941 us; speedup 1.0000x reference)
//
#include <hip/hip_runtime.h>
#include <math.h>

#define NB 8
#define IC 256
#define CC 64
#define HH 128
#define WW 128
#define NN (HH*WW)      // 16384
#define NKW 64          // k-chunks for gramW (8192/64 = 128 k per chunk)
#define NKC 64          // n-chunks for gramC (16384/64 = 256 n per chunk)

// ---------------- workspace layout (floats) ----------------
static constexpr size_t SZ_INP  = (size_t)NB * CC * NN;            // 8,388,608
static constexpr size_t OFF_INP = 0;
static constexpr size_t OFF_S   = OFF_INP + SZ_INP;                // s AND pW (aliased)
static constexpr size_t OFF_PC  = OFF_S + SZ_INP;                  // pC: NB*NKC*4096
static constexpr size_t OFF_TW  = OFF_PC + (size_t)NB * NKC * 4096;
static constexpr size_t OFF_TC  = OFF_TW + (size_t)NB * 16384;
static constexpr size_t OFF_WT  = OFF_TC + (size_t)NB * 4096;      // w_in_t [256 i][64 o]
static constexpr size_t OFF_WOT = OFF_WT + 16384;                  // w_out_t [64 c][256 o]

// ---------------- tiny transpose of both weight matrices ----------------
__global__ __launch_bounds__(256) void k_wt(
    const float* __restrict__ w_in, const float* __restrict__ w_out,
    float* __restrict__ w_in_t, float* __restrict__ w_out_t)
{
    const int idx = blockIdx.x * 256 + threadIdx.x;   // 0..32767
    if (idx < 16384) {
        const int o = idx & 63, i = idx >> 6;         // w_in_t[i][o] = w_in[o][i]
        w_in_t[idx] = w_in[o * IC + i];
    } else {
        const int j = idx - 16384;
        const int o = j & 255, c = j >> 8;            // w_out_t[c][o] = w_out[o][c]
        w_out_t[j] = w_out[o * CC + c];
    }
}

// ---------------- inconv: inp[b,o,n] = sum_i w_in[o,i]*x[b,i,n] + b_in[o] ----------------
// grid (NN/256, NB), block 256. Tile 64o x 256n, 8x8/thread.
// K-chunk 16 (LDS 20.9 KB) + register double-buffer staging.
// launch_bounds(256,2): do NOT cap VGPRs below ~110 — (256,4) in round 4 forced a
// 64-VGPR budget and spilled acc[8][8] to scratch (+120 MB HBM writes, dur +19us).
__global__ __launch_bounds__(256, 2) void k_inconv(
    const float* __restrict__ x, const float* __restrict__ wt,
    const float* __restrict__ b_in, float* __restrict__ inp)
{
    __shared__ float xs[16 * 260];   // [i][n], stride 260
    __shared__ float wl[16 * 68];    // [i][o], stride 68
    const int b  = blockIdx.y;
    const int n0 = blockIdx.x * 256;
    const int t  = threadIdx.x;
    const int og = t >> 5;           // 0..7 : o = og*8..+8 (broadcast per half-wave)
    const int ng = t & 31;           // n cols: n0+ng*4 and n0+128+ng*4

    // staging map: row sr (0..15), col quad sc; x row = 4 float4 at stride 64
    const int sr = t >> 4, sc = (t & 15) * 4;
    const float* xbase = x + ((size_t)b * IC + sr) * NN + n0 + sc;
    const float* wbase = wt + (size_t)sr * 64 + sc;
    float* xdst = xs + sr * 260 + sc;
    float* wdst = wl + sr * 68 + sc;

    float4 gx[4];
    float4 gw;
#pragma unroll
    for (int k = 0; k < 4; k++) gx[k] = *(const float4*)(xbase + 64 * k);
    gw = *(const float4*)(wbase);

    float acc[8][8];
#pragma unroll
    for (int p = 0; p < 8; p++)
#pragma unroll
        for (int q = 0; q < 8; q++) acc[p][q] = 0.f;

    for (int i0 = 0; i0 < IC; i0 += 16) {
        __syncthreads();             // previous compute done reading LDS
#pragma unroll
        for (int k = 0; k < 4; k++) *(float4*)(xdst + 64 * k) = gx[k];
        *(float4*)(wdst) = gw;
        if (i0 + 16 < IC) {          // issue next chunk; waits at next ds_write
            const float* xsrc = xbase + (size_t)(i0 + 16) * NN;
#pragma unroll
            for (int k = 0; k < 4; k++) gx[k] = *(const float4*)(xsrc + 64 * k);
            gw = *(const float4*)(wbase + (size_t)(i0 + 16) * 64);
        }
        __syncthreads();             // LDS filled
#pragma unroll 4
        for (int i = 0; i < 16; ++i) {
            const float4 wa = *(const float4*)(wl + i * 68 + og * 8);
            const float4 wb = *(const float4*)(wl + i * 68 + og * 8 + 4);
            const float4 xa = *(const float4*)(xs + i * 260 + ng * 4);
            const float4 xb = *(const float4*)(xs + i * 260 + 128 + ng * 4);
            const float wv[8] = {wa.x, wa.y, wa.z, wa.w, wb.x, wb.y, wb.z, wb.w};
            const float xv[8] = {xa.x, xa.y, xa.z, xa.w, xb.x, xb.y, xb.z, xb.w};
#pragma unroll
            for (int p = 0; p < 8; p++)
#pragma unroll
                for (int q = 0; q < 8; q++) acc[p][q] += wv[p] * xv[q];
        }
    }
#pragma unroll
    for (int p = 0; p < 8; ++p) {
        const int oo = og * 8 + p;
        const float bo = b_in[oo];
        float* base = inp + ((size_t)b * CC + oo) * NN + n0;
        *(float4*)(base + ng * 4) =
            make_float4(acc[p][0] + bo, acc[p][1] + bo, acc[p][2] + bo, acc[p][3] + bo);
        *(float4*)(base + 128 + ng * 4) =
            make_float4(acc[p][4] + bo, acc[p][5] + bo, acc[p][6] + bo, acc[p][7] + bo);
    }
}

// ---------------- gram W partials ----------------
__global__ __launch_bounds__(256) void k_gramW(const float* __restrict__ inp, float* __restrict__ pW)
{
    __shared__ float xs[8 * 128];
    const int b = blockIdx.y, kc = blockIdx.x;
    const int t = threadIdx.x, tx = t & 15, ty = t >> 4;
    const float* Xb = inp + (size_t)b * CC * NN;
    const int k0 = kc * ((CC * HH) / NKW);   // 128 k per chunk

    float acc[8][8];
#pragma unroll
    for (int i = 0; i < 8; i++)
#pragma unroll
        for (int j = 0; j < 8; j++) acc[i][j] = 0.f;

    for (int kk = k0; kk < k0 + (CC * HH) / NKW; kk += 8) {
        __syncthreads();
        for (int idx = t; idx < 1024; idx += 256)
            xs[idx] = Xb[((size_t)kk + (idx >> 7)) * WW + (idx & 127)];
        __syncthreads();
#pragma unroll
        for (int k = 0; k < 8; k++) {
            const float* row = xs + k * 128;
            float4 t0 = *(const float4*)(row + ty * 8);
            float4 t1 = *(const float4*)(row + ty * 8 + 4);
            float4 u0 = *(const float4*)(row + tx * 8);
            float4 u1 = *(const float4*)(row + tx * 8 + 4);
            float av[8] = {t0.x, t0.y, t0.z, t0.w, t1.x, t1.y, t1.z, t1.w};
            float bv[8] = {u0.x, u0.y, u0.z, u0.w, u1.x, u1.y, u1.z, u1.w};
#pragma unroll
            for (int i = 0; i < 8; i++)
#pragma unroll
                for (int j = 0; j < 8; j++) acc[i][j] += av[i] * bv[j];
        }
    }
    float* dst = pW + ((size_t)b * NKW + kc) * 16384;
#pragma unroll
    for (int i = 0; i < 8; i++)
#pragma unroll
        for (int j = 0; j < 8; j += 4) {
            float4 v = make_float4(acc[i][j], acc[i][j + 1], acc[i][j + 2], acc[i][j + 3]);
            *(float4*)(dst + (ty * 8 + i) * 128 + tx * 8 + j) = v;
        }
}

__global__ __launch_bounds__(256) void k_redW(const float* __restrict__ pW, float* __restrict__ Tw)
{
    const int b = blockIdx.y;
    const int idx = blockIdx.x * 256 + threadIdx.x;
    const float* p = pW + (size_t)b * NKW * 16384 + idx;
    float acc = 0.f;
#pragma unroll
    for (int k = 0; k < NKW; k++) acc += p[(size_t)k * 16384];
    Tw[(size_t)b * 16384 + idx] = acc;
}

// softmax over w (rows) per column v; grid (NB, 4), block 1024: 32 v-cols x 128 rows
__global__ __launch_bounds__(1024) void k_softW(float* __restrict__ Tw)
{
    __shared__ float red[32 * 33];
    const int b = blockIdx.x, v0 = blockIdx.y * 32;
    const int t = threadIdx.x;
    const int vc = t & 31, wg = t >> 5;      // 32 row-groups x 4 rows
    float* S = Tw + (size_t)b * 16384 + v0 + vc;

    float v[4];
    float m = -3.4e38f;
#pragma unroll
    for (int j = 0; j < 4; j++) { v[j] = S[(wg * 4 + j) * 128]; m = fmaxf(m, v[j]); }
    red[wg * 33 + vc] = m;
    __syncthreads();
    for (int st = 16; st > 0; st >>= 1) {
        if (wg < st) red[wg * 33 + vc] = fmaxf(red[wg * 33 + vc], red[(wg + st) * 33 + vc]);
        __syncthreads();
    }
    m = red[vc];
    __syncthreads();
    float sum = 0.f;
#pragma unroll
    for (int j = 0; j < 4; j++) { v[j] = __expf(v[j] - m); sum += v[j]; }
    red[wg * 33 + vc] = sum;
    __syncthreads();
    for (int st = 16; st > 0; st >>= 1) {
        if (wg < st) red[wg * 33 + vc] += red[(wg + st) * 33 + vc];
        __syncthreads();
    }
    const float inv = 1.f / red[vc];
#pragma unroll
    for (int j = 0; j < 4; j++) S[(wg * 4 + j) * 128] = v[j] * inv;
}

// ---------------- gram C partials: transposed LDS tile [n][c] ----------------
__global__ __launch_bounds__(256) void k_gramC(const float* __restrict__ inp, float* __restrict__ pC)
{
    __shared__ float xt[32 * 68];   // [n_local][c], stride 68
    const int b = blockIdx.y, nc = blockIdx.x;
    const int t = threadIdx.x, tx = t & 15, ty = t >> 4;
    const float* ip = inp + (size_t)b * CC * NN;
    const int n0 = nc * (NN / NKC);

    float acc[4][4];
#pragma unroll
    for (int i = 0; i < 4; i++)
#pragma unroll
        for (int j = 0; j < 4; j++) acc[i][j] = 0.f;

    const int scc = t >> 2;
    const int sn  = (t & 3) * 8;

    for (int nt = 0; nt < NN / NKC; nt += 32) {
        __syncthreads();
        {
            const float* src = ip + (size_t)scc * NN + n0 + nt + sn;
            float v[8];
            *(float4*)(v)     = *(const float4*)(src);
            *(float4*)(v + 4) = *(const float4*)(src + 4);
#pragma unroll
            for (int j = 0; j < 8; j++) xt[(sn + j) * 68 + scc] = v[j];
        }
        __syncthreads();
#pragma unroll 8
        for (int nn = 0; nn < 32; nn++) {
            const float4 a4 = *(const float4*)(xt + nn * 68 + ty * 4);
            const float4 e4 = *(const float4*)(xt + nn * 68 + tx * 4);
            const float av[4] = {a4.x, a4.y, a4.z, a4.w};
            const float ev[4] = {e4.x, e4.y, e4.z, e4.w};
#pragma unroll
            for (int i = 0; i < 4; i++)
#pragma unroll
                for (int j = 0; j < 4; j++) acc[i][j] += av[i] * ev[j];
        }
    }
    float* dst = pC + ((size_t)b * NKC + nc) * 4096;
#pragma unroll
    for (int i = 0; i < 4; i++) {
        float4 v = make_float4(acc[i][0], acc[i][1], acc[i][2], acc[i][3]);
        *(float4*)(dst + (ty * 4 + i) * 64 + tx * 4) = v;
    }
}

__global__ __launch_bounds__(256) void k_redC(const float* __restrict__ pC, float* __restrict__ Tc)
{
    const int b = blockIdx.y;
    const int idx = blockIdx.x * 256 + threadIdx.x;
    const float* p = pC + (size_t)b * NKC * 4096 + idx;
    float acc = 0.f;
#pragma unroll
    for (int k = 0; k < NKC; k++) acc += p[(size_t)k * 4096];
    Tc[(size_t)b * 4096 + idx] = acc;
}

// softmax over c (rows) per column d; grid (NB), block 1024: 64 d-cols x 64 rows
__global__ __launch_bounds__(1024) void k_softC(float* __restrict__ Tc)
{
    __shared__ float red[16 * 65];
    const int b = blockIdx.x;
    const int t = threadIdx.x;
    const int dc = t & 63, cg = t >> 6;     // 16 row-groups x 4 rows
    float* S = Tc + (size_t)b * 4096 + dc;

    float v[4];
    float m = -3.4e38f;
#pragma unroll
    for (int j = 0; j < 4; j++) { v[j] = S[(cg * 4 + j) * 64]; m = fmaxf(m, v[j]); }
    red[cg * 65 + dc] = m;
    __syncthreads();
    for (int st = 8; st > 0; st >>= 1) {
        if (cg < st) red[cg * 65 + dc] = fmaxf(red[cg * 65 + dc], red[(cg + st) * 65 + dc]);
        __syncthreads();
    }
    m = red[dc];
    __syncthreads();
    float sum = 0.f;
#pragma unroll
    for (int j = 0; j < 4; j++) { v[j] = __expf(v[j] - m); sum += v[j]; }
    red[cg * 65 + dc] = sum;
    __syncthreads();
    for (int st = 8; st > 0; st >>= 1) {
        if (cg < st) red[cg * 65 + dc] += red[(cg + st) * 65 + dc];
        __syncthreads();
    }
    const float inv = 1.f / red[dc];
#pragma unroll
    for (int j = 0; j < 4; j++) S[(cg * 4 + j) * 64] = v[j] * inv;
}

// ---------------- Co: s_flat[b][n*64+d] = detal * sum_c inp[b,c,n]*Tc[c,d] ----------------
__global__ __launch_bounds__(256) void k_co(
    const float* __restrict__ inp, const float* __restrict__ Tc,
    const float* __restrict__ detal, float* __restrict__ s)
{
    __shared__ float tc[64 * 68];    // [c][d], stride 68
    __shared__ float xs[64 * 132];   // [c][n], stride 132
    const int b  = blockIdx.y;
    const int n0 = blockIdx.x * 128;
    const int t  = threadIdx.x;
    const int d4 = (t & 15) * 4;
    const int g8 = (t >> 4) * 8;

    {
        const int sr = t >> 2, sc = (t & 3) * 4;
        const float* src = inp + ((size_t)b * CC + sr) * NN + n0;
        float* dst = xs + sr * 132;
#pragma unroll
        for (int k = 0; k < 8; k++)
            *(float4*)(dst + sc + 16 * k) = *(const float4*)(src + sc + 16 * k);
        const float* tsrc = Tc + (size_t)b * 4096 + sr * 64;
        float* tdst = tc + sr * 68;
#pragma unroll
        for (int k = 0; k < 4; k++)
            *(float4*)(tdst + sc + 16 * k) = *(const float4*)(tsrc + sc + 16 * k);
    }
    __syncthreads();

    float acc[8][4];
#pragma unroll
    for (int i = 0; i < 8; i++)
#pragma unroll
        for (int j = 0; j < 4; j++) acc[i][j] = 0.f;

#pragma unroll 4
    for (int c = 0; c < 64; c++) {
        const float4 t4 = *(const float4*)(tc + c * 68 + d4);
        const float4 xa = *(const float4*)(xs + c * 132 + g8);
        const float4 xb = *(const float4*)(xs + c * 132 + g8 + 4);
        const float xv[8] = {xa.x, xa.y, xa.z, xa.w, xb.x, xb.y, xb.z, xb.w};
        const float tv[4] = {t4.x, t4.y, t4.z, t4.w};
#pragma unroll
        for (int i = 0; i < 8; i++)
#pragma unroll
            for (int j = 0; j < 4; j++) acc[i][j] += xv[i] * tv[j];
    }
    const float scl = detal[0];
    float* sb = s + (size_t)b * CC * NN + (size_t)n0 * 64;
#pragma unroll
    for (int i = 0; i < 8; i++) {
        float4 v = make_float4(acc[i][0] * scl, acc[i][1] * scl,
                               acc[i][2] * scl, acc[i][3] * scl);
        *(float4*)(sb + (size_t)(g8 + i) * 64 + d4) = v;
    }
}

// ---------------- Wo (==Ho): s[b,c,h,v] += 2*detal * sum_w inp[b,c,h,w]*Tw[w,v] ----------------
// grid (CC, NB), block 256. Tile 128h x 128v, 8x8 per thread, K=128 in 4 chunks of 32.
// X staged transposed [w][h] (stride 132); Tw staged [w][v] (stride 132).
__global__ __launch_bounds__(256, 2) void k_wo(
    const float* __restrict__ inp, const float* __restrict__ Tw,
    const float* __restrict__ detal, float* __restrict__ s)
{
    __shared__ float xt[32 * 132];    // [w][h]
    __shared__ float twl[32 * 132];   // [w][v]
    const int b = blockIdx.y, c = blockIdx.x;
    const int t = threadIdx.x;
    const int rg = t >> 4;            // 0..15 : h = rg*8..+8
    const int vg = t & 15;            // v cols: vg*4 and 64+vg*4

    const float* ip = inp + ((size_t)b * CC + c) * NN;
    const float* twg = Tw + (size_t)b * 16384;

    float acc[8][8];
#pragma unroll
    for (int p = 0; p < 8; p++)
#pragma unroll
        for (int q = 0; q < 8; q++) acc[p][q] = 0.f;

    for (int w0 = 0; w0 < 128; w0 += 32) {
        __syncthreads();
        {   // stage X^T: rows h=0..127, w-chunk 32; thread: h=t>>1, 16 w's
            const int h = t >> 1, wq = (t & 1) * 16;
            const float* src = ip + (size_t)h * WW + w0 + wq;
            float v[16];
            *(float4*)(v)      = *(const float4*)(src);
            *(float4*)(v + 4)  = *(const float4*)(src + 4);
            *(float4*)(v + 8)  = *(const float4*)(src + 8);
            *(float4*)(v + 12) = *(const float4*)(src + 12);
#pragma unroll
            for (int j = 0; j < 16; j++) xt[(wq + j) * 132 + h] = v[j];
        }
        {   // stage Tw rows: [w][v]; thread: w=t>>3, 16 v's
            const int w = t >> 3, cq = (t & 7) * 16;
            const float* src = twg + (size_t)(w0 + w) * 128 + cq;
            float* dst = twl + w * 132 + cq;
#pragma unroll
            for (int k = 0; k < 4; k++)
                *(float4*)(dst + 4 * k) = *(const float4*)(src + 4 * k);
        }
        __syncthreads();
#pragma unroll 4
        for (int w = 0; w < 32; ++w) {
            const float4 ra = *(const float4*)(xt + w * 132 + rg * 8);
            const float4 rb = *(const float4*)(xt + w * 132 + rg * 8 + 4);
            const float4 ta = *(const float4*)(twl + w * 132 + vg * 4);
            const float4 tb = *(const float4*)(twl + w * 132 + 64 + vg * 4);
            const float rv[8] = {ra.x, ra.y, ra.z, ra.w, rb.x, rb.y, rb.z, rb.w};
            const float tv[8] = {ta.x, ta.y, ta.z, ta.w, tb.x, tb.y, tb.z, tb.w};
#pragma unroll
            for (int p = 0; p < 8; p++)
#pragma unroll
                for (int q = 0; q < 8; q++) acc[p][q] += rv[p] * tv[q];
        }
    }

    const float sc2 = 2.0f * detal[0];
    float* sp = s + ((size_t)b * CC + c) * NN;
#pragma unroll
    for (int p = 0; p < 8; ++p) {
        const int h = rg * 8 + p;
        float* q0 = sp + (size_t)h * WW + vg * 4;
        float* q1 = sp + (size_t)h * WW + 64 + vg * 4;
        float4 c0 = *(const float4*)q0;
        float4 c1 = *(const float4*)q1;
        c0.x += sc2 * acc[p][0]; c0.y += sc2 * acc[p][1];
        c0.z += sc2 * acc[p][2]; c0.w += sc2 * acc[p][3];
        c1.x += sc2 * acc[p][4]; c1.y += sc2 * acc[p][5];
        c1.z += sc2 * acc[p][6]; c1.w += sc2 * acc[p][7];
        *(float4*)q0 = c0;
        *(float4*)q1 = c1;
    }
}

// ---------------- outconv: out[b,o,n] = sum_c w_out[o,c]*s[b,c,n] + b_out[o] + x[b,o,n] ----------------
// grid (NN/256, 4, NB), block 256. K-chunk-16 double-buffered; launch_bounds(256,2)
// (see k_inconv note: (256,4) caused acc spill to scratch in round 4).
__global__ __launch_bounds__(256, 2) void k_outconv(
    const float* __restrict__ s, const float* __restrict__ wot,
    const float* __restrict__ b_out, const float* __restrict__ x,
    float* __restrict__ outp)
{
    __shared__ float ss[16 * 260];   // [c][n], stride 260
    __shared__ float wl[16 * 68];    // [c][o_local], stride 68
    const int b  = blockIdx.z;
    const int o0 = blockIdx.y * 64;
    const int n0 = blockIdx.x * 256;
    const int t  = threadIdx.x;
    const int og = t >> 5;           // 0..7
    const int ng = t & 31;

    const int sr = t >> 4, sc = (t & 15) * 4;
    const float* sbase = s + ((size_t)b * CC + sr) * NN + n0 + sc;
    const float* wbase = wot + (size_t)sr * IC + o0 + sc;
    float* sdst = ss + sr * 260 + sc;
    float* wdst = wl + sr * 68 + sc;

    float4 gs[4];
    float4 gw;
#pragma unroll
    for (int k = 0; k < 4; k++) gs[k] = *(const float4*)(sbase + 64 * k);
    gw = *(const float4*)(wbase);

    float acc[8][8];
#pragma unroll
    for (int p = 0; p < 8; p++)
#pragma unroll
        for (int q = 0; q < 8; q++) acc[p][q] = 0.f;

    for (int c0 = 0; c0 < CC; c0 += 16) {
        __syncthreads();
#pragma unroll
        for (int k = 0; k < 4; k++) *(float4*)(sdst + 64 * k) = gs[k];
        *(float4*)(wdst) = gw;
        if (c0 + 16 < CC) {
            const float* ssrc = sbase + (size_t)(c0 + 16) * NN;
#pragma unroll
            for (int k = 0; k < 4; k++) gs[k] = *(const float4*)(ssrc + 64 * k);
            gw = *(const float4*)(wbase + (size_t)(c0 + 16) * IC);
        }
        __syncthreads();
#pragma unroll 4
        for (int c = 0; c < 16; ++c) {
            const float4 wa = *(const float4*)(wl + c * 68 + og * 8);
            const float4 wb = *(const float4*)(wl + c * 68 + og * 8 + 4);
            const float4 sa = *(const float4*)(ss + c * 260 + ng * 4);
            const float4 sb = *(const float4*)(ss + c * 260 + 128 + ng * 4);
            const float wv[8] = {wa.x, wa.y, wa.z, wa.w, wb.x, wb.y, wb.z, wb.w};
            const float sv[8] = {sa.x, sa.y, sa.z, sa.w, sb.x, sb.y, sb.z, sb.w};
#pragma unroll
            for (int p = 0; p < 8; p++)
#pragma unroll
                for (int q = 0; q < 8; q++) acc[p][q] += wv[p] * sv[q];
        }
    }

#pragma unroll
    for (int p = 0; p < 8; ++p) {
        const int oo = o0 + og * 8 + p;
        const float bo = b_out[oo];
        const float* xb = x + ((size_t)b * IC + oo) * NN + n0;
        float* ob = outp + ((size_t)b * IC + oo) * NN + n0;
        const float4 x0 = *(const float4*)(xb + ng * 4);
        const float4 x1 = *(const float4*)(xb + 128 + ng * 4);
        *(float4*)(ob + ng * 4) =
            make_float4(acc[p][0] + bo + x0.x, acc[p][1] + bo + x0.y,
                        acc[p][2] + bo + x0.z, acc[p][3] + bo + x0.w);
        *(float4*)(ob + 128 + ng * 4) =
            make_float4(acc[p][4] + bo + x1.x, acc[p][5] + bo + x1.y,
                        acc[p][6] + bo + x1.z, acc[p][7] + bo + x1.w);
    }
}

extern "C" void kernel_launch(void* const* d_in, const int* in_sizes, int n_in,
                              void* d_out, int out_size, void* d_ws, size_t ws_size,
                              hipStream_t stream)
{
    const float* x     = (const float*)d_in[0];
    const float* w_in  = (const float*)d_in[1];
    const float* b_in  = (const float*)d_in[2];
    const float* w_out = (const float*)d_in[3];
    const float* b_out = (const float*)d_in[4];
    const float* detal = (const float*)d_in[5];
    float* out = (float*)d_out;

    float* ws   = (float*)d_ws;
    float* inp  = ws + OFF_INP;
    float* s    = ws + OFF_S;
    float* pW   = ws + OFF_S;      // aliased with s (pW dead before k_co writes s)
    float* pC   = ws + OFF_PC;
    float* Tw   = ws + OFF_TW;
    float* Tc   = ws + OFF_TC;
    float* wt   = ws + OFF_WT;
    float* wot  = ws + OFF_WOT;

    k_wt     <<<dim3(128),              256, 0, stream>>>(w_in, w_out, wt, wot);
    k_inconv <<<dim3(NN / 256, NB),     256, 0, stream>>>(x, wt, b_in, inp);
    k_gramW  <<<dim3(NKW, NB),          256, 0, stream>>>(inp, pW);
    k_redW   <<<dim3(64, NB),           256, 0, stream>>>(pW, Tw);
    k_softW  <<<dim3(NB, 4),           1024, 0, stream>>>(Tw);
    k_gramC  <<<dim3(NKC, NB),          256, 0, stream>>>(inp, pC);
    k_redC   <<<dim3(16, NB),           256, 0, stream>>>(pC, Tc);
    k_softC  <<<dim3(NB),              1024, 0, stream>>>(Tc);
    k_co     <<<dim3(NN / 128, NB),     256, 0, stream>>>(inp, Tc, detal, s);
    k_wo     <<<dim3(CC, NB),           256, 0, stream>>>(inp, Tw, detal, s);
    k_outconv<<<dim3(NN / 256, 4, NB),  256, 0, stream>>>(s, wot, b_out, x, out);
}

// Round 6
// 445.850 us; speedup vs baseline: 1.1482x; 1.1482x over previous
//
#include <hip/hip_runtime.h>
#include <math.h>

#define NB 8
#define IC 256
#define CC 64
#define HH 128
#define WW 128
#define NN (HH*WW)      // 16384
#define NKW 64          // k-chunks for gramW (8192/64 = 128 k per chunk)
#define NKC 64          // n-chunks for gramC (16384/64 = 256 n per chunk)

// ---------------- workspace layout (floats) ----------------
static constexpr size_t SZ_INP  = (size_t)NB * CC * NN;            // 8,388,608
static constexpr size_t OFF_INP = 0;
static constexpr size_t OFF_S   = OFF_INP + SZ_INP;                // s AND pW (aliased)
static constexpr size_t OFF_PC  = OFF_S + SZ_INP;                  // pC: NB*NKC*4096
static constexpr size_t OFF_TW  = OFF_PC + (size_t)NB * NKC * 4096;
static constexpr size_t OFF_TC  = OFF_TW + (size_t)NB * 16384;
static constexpr size_t OFF_WT  = OFF_TC + (size_t)NB * 4096;      // w_in_t [256 i][64 o]
static constexpr size_t OFF_WOT = OFF_WT + 16384;                  // w_out_t [64 c][256 o]

// ---------------- tiny transpose of both weight matrices ----------------
__global__ __launch_bounds__(256) void k_wt(
    const float* __restrict__ w_in, const float* __restrict__ w_out,
    float* __restrict__ w_in_t, float* __restrict__ w_out_t)
{
    const int idx = blockIdx.x * 256 + threadIdx.x;   // 0..32767
    if (idx < 16384) {
        const int o = idx & 63, i = idx >> 6;         // w_in_t[i][o] = w_in[o][i]
        w_in_t[idx] = w_in[o * IC + i];
    } else {
        const int j = idx - 16384;
        const int o = j & 255, c = j >> 8;            // w_out_t[c][o] = w_out[o][c]
        w_out_t[j] = w_out[o * CC + c];
    }
}

// ---------------- inconv: inp[b,o,n] = sum_i w_in[o,i]*x[b,i,n] + b_in[o] ----------------
// grid (NN/256, NB), block 256. Tile 64o x 256n, 8x8/thread, K-chunk 16 (LDS 21 KB).
// DIRECT staging (load -> immediate LDS store, short-lived regs): rounds 4/5 proved the
// persistent-register prefetch spills acc to scratch (~112 MB HBM, +20us) regardless of
// launch_bounds. Latency is hidden by occupancy (~5 blocks/CU at 21 KB LDS / ~96 VGPR).
__global__ __launch_bounds__(256) void k_inconv(
    const float* __restrict__ x, const float* __restrict__ wt,
    const float* __restrict__ b_in, float* __restrict__ inp)
{
    __shared__ float xs[16 * 260];   // [i][n], stride 260
    __shared__ float wl[16 * 68];    // [i][o], stride 68
    const int b  = blockIdx.y;
    const int n0 = blockIdx.x * 256;
    const int t  = threadIdx.x;
    const int og = t >> 5;           // 0..7 : o = og*8..+8 (broadcast per half-wave)
    const int ng = t & 31;           // n cols: n0+ng*4 and n0+128+ng*4

    // staging map: row sr (0..15), col quad sc; x row = 4 float4 at stride 64
    const int sr = t >> 4, sc = (t & 15) * 4;
    const float* xbase = x + ((size_t)b * IC + sr) * NN + n0 + sc;
    const float* wbase = wt + (size_t)sr * 64 + sc;
    float* xdst = xs + sr * 260 + sc;
    float* wdst = wl + sr * 68 + sc;

    float acc[8][8];
#pragma unroll
    for (int p = 0; p < 8; p++)
#pragma unroll
        for (int q = 0; q < 8; q++) acc[p][q] = 0.f;

    for (int i0 = 0; i0 < IC; i0 += 16) {
        __syncthreads();             // previous compute done reading LDS
        {
            const float* xsrc = xbase + (size_t)i0 * NN;
            const float4 a0 = *(const float4*)(xsrc);
            const float4 a1 = *(const float4*)(xsrc + 64);
            const float4 a2 = *(const float4*)(xsrc + 128);
            const float4 a3 = *(const float4*)(xsrc + 192);
            const float4 w0 = *(const float4*)(wbase + (size_t)i0 * 64);
            *(float4*)(xdst)       = a0;
            *(float4*)(xdst + 64)  = a1;
            *(float4*)(xdst + 128) = a2;
            *(float4*)(xdst + 192) = a3;
            *(float4*)(wdst)       = w0;
        }
        __syncthreads();             // LDS filled
#pragma unroll 4
        for (int i = 0; i < 16; ++i) {
            const float4 wa = *(const float4*)(wl + i * 68 + og * 8);
            const float4 wb = *(const float4*)(wl + i * 68 + og * 8 + 4);
            const float4 xa = *(const float4*)(xs + i * 260 + ng * 4);
            const float4 xb = *(const float4*)(xs + i * 260 + 128 + ng * 4);
            const float wv[8] = {wa.x, wa.y, wa.z, wa.w, wb.x, wb.y, wb.z, wb.w};
            const float xv[8] = {xa.x, xa.y, xa.z, xa.w, xb.x, xb.y, xb.z, xb.w};
#pragma unroll
            for (int p = 0; p < 8; p++)
#pragma unroll
                for (int q = 0; q < 8; q++) acc[p][q] += wv[p] * xv[q];
        }
    }
#pragma unroll
    for (int p = 0; p < 8; ++p) {
        const int oo = og * 8 + p;
        const float bo = b_in[oo];
        float* base = inp + ((size_t)b * CC + oo) * NN + n0;
        *(float4*)(base + ng * 4) =
            make_float4(acc[p][0] + bo, acc[p][1] + bo, acc[p][2] + bo, acc[p][3] + bo);
        *(float4*)(base + 128 + ng * 4) =
            make_float4(acc[p][4] + bo, acc[p][5] + bo, acc[p][6] + bo, acc[p][7] + bo);
    }
}

// ---------------- gram W partials ----------------
__global__ __launch_bounds__(256) void k_gramW(const float* __restrict__ inp, float* __restrict__ pW)
{
    __shared__ float xs[8 * 128];
    const int b = blockIdx.y, kc = blockIdx.x;
    const int t = threadIdx.x, tx = t & 15, ty = t >> 4;
    const float* Xb = inp + (size_t)b * CC * NN;
    const int k0 = kc * ((CC * HH) / NKW);   // 128 k per chunk

    float acc[8][8];
#pragma unroll
    for (int i = 0; i < 8; i++)
#pragma unroll
        for (int j = 0; j < 8; j++) acc[i][j] = 0.f;

    for (int kk = k0; kk < k0 + (CC * HH) / NKW; kk += 8) {
        __syncthreads();
        for (int idx = t; idx < 1024; idx += 256)
            xs[idx] = Xb[((size_t)kk + (idx >> 7)) * WW + (idx & 127)];
        __syncthreads();
#pragma unroll
        for (int k = 0; k < 8; k++) {
            const float* row = xs + k * 128;
            float4 t0 = *(const float4*)(row + ty * 8);
            float4 t1 = *(const float4*)(row + ty * 8 + 4);
            float4 u0 = *(const float4*)(row + tx * 8);
            float4 u1 = *(const float4*)(row + tx * 8 + 4);
            float av[8] = {t0.x, t0.y, t0.z, t0.w, t1.x, t1.y, t1.z, t1.w};
            float bv[8] = {u0.x, u0.y, u0.z, u0.w, u1.x, u1.y, u1.z, u1.w};
#pragma unroll
            for (int i = 0; i < 8; i++)
#pragma unroll
                for (int j = 0; j < 8; j++) acc[i][j] += av[i] * bv[j];
        }
    }
    float* dst = pW + ((size_t)b * NKW + kc) * 16384;
#pragma unroll
    for (int i = 0; i < 8; i++)
#pragma unroll
        for (int j = 0; j < 8; j += 4) {
            float4 v = make_float4(acc[i][j], acc[i][j + 1], acc[i][j + 2], acc[i][j + 3]);
            *(float4*)(dst + (ty * 8 + i) * 128 + tx * 8 + j) = v;
        }
}

__global__ __launch_bounds__(256) void k_redW(const float* __restrict__ pW, float* __restrict__ Tw)
{
    const int b = blockIdx.y;
    const int idx = blockIdx.x * 256 + threadIdx.x;
    const float* p = pW + (size_t)b * NKW * 16384 + idx;
    float acc = 0.f;
#pragma unroll
    for (int k = 0; k < NKW; k++) acc += p[(size_t)k * 16384];
    Tw[(size_t)b * 16384 + idx] = acc;
}

// softmax over w (rows) per column v; grid (NB, 4), block 1024: 32 v-cols x 128 rows
__global__ __launch_bounds__(1024) void k_softW(float* __restrict__ Tw)
{
    __shared__ float red[32 * 33];
    const int b = blockIdx.x, v0 = blockIdx.y * 32;
    const int t = threadIdx.x;
    const int vc = t & 31, wg = t >> 5;      // 32 row-groups x 4 rows
    float* S = Tw + (size_t)b * 16384 + v0 + vc;

    float v[4];
    float m = -3.4e38f;
#pragma unroll
    for (int j = 0; j < 4; j++) { v[j] = S[(wg * 4 + j) * 128]; m = fmaxf(m, v[j]); }
    red[wg * 33 + vc] = m;
    __syncthreads();
    for (int st = 16; st > 0; st >>= 1) {
        if (wg < st) red[wg * 33 + vc] = fmaxf(red[wg * 33 + vc], red[(wg + st) * 33 + vc]);
        __syncthreads();
    }
    m = red[vc];
    __syncthreads();
    float sum = 0.f;
#pragma unroll
    for (int j = 0; j < 4; j++) { v[j] = __expf(v[j] - m); sum += v[j]; }
    red[wg * 33 + vc] = sum;
    __syncthreads();
    for (int st = 16; st > 0; st >>= 1) {
        if (wg < st) red[wg * 33 + vc] += red[(wg + st) * 33 + vc];
        __syncthreads();
    }
    const float inv = 1.f / red[vc];
#pragma unroll
    for (int j = 0; j < 4; j++) S[(wg * 4 + j) * 128] = v[j] * inv;
}

// ---------------- gram C partials: transposed LDS tile [n][c] ----------------
__global__ __launch_bounds__(256) void k_gramC(const float* __restrict__ inp, float* __restrict__ pC)
{
    __shared__ float xt[32 * 68];   // [n_local][c], stride 68
    const int b = blockIdx.y, nc = blockIdx.x;
    const int t = threadIdx.x, tx = t & 15, ty = t >> 4;
    const float* ip = inp + (size_t)b * CC * NN;
    const int n0 = nc * (NN / NKC);

    float acc[4][4];
#pragma unroll
    for (int i = 0; i < 4; i++)
#pragma unroll
        for (int j = 0; j < 4; j++) acc[i][j] = 0.f;

    const int scc = t >> 2;
    const int sn  = (t & 3) * 8;

    for (int nt = 0; nt < NN / NKC; nt += 32) {
        __syncthreads();
        {
            const float* src = ip + (size_t)scc * NN + n0 + nt + sn;
            float v[8];
            *(float4*)(v)     = *(const float4*)(src);
            *(float4*)(v + 4) = *(const float4*)(src + 4);
#pragma unroll
            for (int j = 0; j < 8; j++) xt[(sn + j) * 68 + scc] = v[j];
        }
        __syncthreads();
#pragma unroll 8
        for (int nn = 0; nn < 32; nn++) {
            const float4 a4 = *(const float4*)(xt + nn * 68 + ty * 4);
            const float4 e4 = *(const float4*)(xt + nn * 68 + tx * 4);
            const float av[4] = {a4.x, a4.y, a4.z, a4.w};
            const float ev[4] = {e4.x, e4.y, e4.z, e4.w};
#pragma unroll
            for (int i = 0; i < 4; i++)
#pragma unroll
                for (int j = 0; j < 4; j++) acc[i][j] += av[i] * ev[j];
        }
    }
    float* dst = pC + ((size_t)b * NKC + nc) * 4096;
#pragma unroll
    for (int i = 0; i < 4; i++) {
        float4 v = make_float4(acc[i][0], acc[i][1], acc[i][2], acc[i][3]);
        *(float4*)(dst + (ty * 4 + i) * 64 + tx * 4) = v;
    }
}

__global__ __launch_bounds__(256) void k_redC(const float* __restrict__ pC, float* __restrict__ Tc)
{
    const int b = blockIdx.y;
    const int idx = blockIdx.x * 256 + threadIdx.x;
    const float* p = pC + (size_t)b * NKC * 4096 + idx;
    float acc = 0.f;
#pragma unroll
    for (int k = 0; k < NKC; k++) acc += p[(size_t)k * 4096];
    Tc[(size_t)b * 4096 + idx] = acc;
}

// softmax over c (rows) per column d; grid (NB), block 1024: 64 d-cols x 64 rows
__global__ __launch_bounds__(1024) void k_softC(float* __restrict__ Tc)
{
    __shared__ float red[16 * 65];
    const int b = blockIdx.x;
    const int t = threadIdx.x;
    const int dc = t & 63, cg = t >> 6;     // 16 row-groups x 4 rows
    float* S = Tc + (size_t)b * 4096 + dc;

    float v[4];
    float m = -3.4e38f;
#pragma unroll
    for (int j = 0; j < 4; j++) { v[j] = S[(cg * 4 + j) * 64]; m = fmaxf(m, v[j]); }
    red[cg * 65 + dc] = m;
    __syncthreads();
    for (int st = 8; st > 0; st >>= 1) {
        if (cg < st) red[cg * 65 + dc] = fmaxf(red[cg * 65 + dc], red[(cg + st) * 65 + dc]);
        __syncthreads();
    }
    m = red[dc];
    __syncthreads();
    float sum = 0.f;
#pragma unroll
    for (int j = 0; j < 4; j++) { v[j] = __expf(v[j] - m); sum += v[j]; }
    red[cg * 65 + dc] = sum;
    __syncthreads();
    for (int st = 8; st > 0; st >>= 1) {
        if (cg < st) red[cg * 65 + dc] += red[(cg + st) * 65 + dc];
        __syncthreads();
    }
    const float inv = 1.f / red[dc];
#pragma unroll
    for (int j = 0; j < 4; j++) S[(cg * 4 + j) * 64] = v[j] * inv;
}

// ---------------- Co: s_flat[b][n*64+d] = detal * sum_c inp[b,c,n]*Tc[c,d] ----------------
__global__ __launch_bounds__(256) void k_co(
    const float* __restrict__ inp, const float* __restrict__ Tc,
    const float* __restrict__ detal, float* __restrict__ s)
{
    __shared__ float tc[64 * 68];    // [c][d], stride 68
    __shared__ float xs[64 * 132];   // [c][n], stride 132
    const int b  = blockIdx.y;
    const int n0 = blockIdx.x * 128;
    const int t  = threadIdx.x;
    const int d4 = (t & 15) * 4;
    const int g8 = (t >> 4) * 8;

    {
        const int sr = t >> 2, sc = (t & 3) * 4;
        const float* src = inp + ((size_t)b * CC + sr) * NN + n0;
        float* dst = xs + sr * 132;
#pragma unroll
        for (int k = 0; k < 8; k++)
            *(float4*)(dst + sc + 16 * k) = *(const float4*)(src + sc + 16 * k);
        const float* tsrc = Tc + (size_t)b * 4096 + sr * 64;
        float* tdst = tc + sr * 68;
#pragma unroll
        for (int k = 0; k < 4; k++)
            *(float4*)(tdst + sc + 16 * k) = *(const float4*)(tsrc + sc + 16 * k);
    }
    __syncthreads();

    float acc[8][4];
#pragma unroll
    for (int i = 0; i < 8; i++)
#pragma unroll
        for (int j = 0; j < 4; j++) acc[i][j] = 0.f;

#pragma unroll 4
    for (int c = 0; c < 64; c++) {
        const float4 t4 = *(const float4*)(tc + c * 68 + d4);
        const float4 xa = *(const float4*)(xs + c * 132 + g8);
        const float4 xb = *(const float4*)(xs + c * 132 + g8 + 4);
        const float xv[8] = {xa.x, xa.y, xa.z, xa.w, xb.x, xb.y, xb.z, xb.w};
        const float tv[4] = {t4.x, t4.y, t4.z, t4.w};
#pragma unroll
        for (int i = 0; i < 8; i++)
#pragma unroll
            for (int j = 0; j < 4; j++) acc[i][j] += xv[i] * tv[j];
    }
    const float scl = detal[0];
    float* sb = s + (size_t)b * CC * NN + (size_t)n0 * 64;
#pragma unroll
    for (int i = 0; i < 8; i++) {
        float4 v = make_float4(acc[i][0] * scl, acc[i][1] * scl,
                               acc[i][2] * scl, acc[i][3] * scl);
        *(float4*)(sb + (size_t)(g8 + i) * 64 + d4) = v;
    }
}

// ---------------- Wo (==Ho): s[b,c,h,v] += 2*detal * sum_w inp[b,c,h,w]*Tw[w,v] ----------------
// grid (CC, NB), block 256. Tile 128h x 128v, 8x8 per thread, K=128 in 4 chunks of 32.
// X staged transposed [w][h] (stride 132); Tw staged [w][v] (stride 132).
__global__ __launch_bounds__(256, 2) void k_wo(
    const float* __restrict__ inp, const float* __restrict__ Tw,
    const float* __restrict__ detal, float* __restrict__ s)
{
    __shared__ float xt[32 * 132];    // [w][h]
    __shared__ float twl[32 * 132];   // [w][v]
    const int b = blockIdx.y, c = blockIdx.x;
    const int t = threadIdx.x;
    const int rg = t >> 4;            // 0..15 : h = rg*8..+8
    const int vg = t & 15;            // v cols: vg*4 and 64+vg*4

    const float* ip = inp + ((size_t)b * CC + c) * NN;
    const float* twg = Tw + (size_t)b * 16384;

    float acc[8][8];
#pragma unroll
    for (int p = 0; p < 8; p++)
#pragma unroll
        for (int q = 0; q < 8; q++) acc[p][q] = 0.f;

    for (int w0 = 0; w0 < 128; w0 += 32) {
        __syncthreads();
        {   // stage X^T: rows h=0..127, w-chunk 32; thread: h=t>>1, 16 w's
            const int h = t >> 1, wq = (t & 1) * 16;
            const float* src = ip + (size_t)h * WW + w0 + wq;
            float v[16];
            *(float4*)(v)      = *(const float4*)(src);
            *(float4*)(v + 4)  = *(const float4*)(src + 4);
            *(float4*)(v + 8)  = *(const float4*)(src + 8);
            *(float4*)(v + 12) = *(const float4*)(src + 12);
#pragma unroll
            for (int j = 0; j < 16; j++) xt[(wq + j) * 132 + h] = v[j];
        }
        {   // stage Tw rows: [w][v]; thread: w=t>>3, 16 v's
            const int w = t >> 3, cq = (t & 7) * 16;
            const float* src = twg + (size_t)(w0 + w) * 128 + cq;
            float* dst = twl + w * 132 + cq;
#pragma unroll
            for (int k = 0; k < 4; k++)
                *(float4*)(dst + 4 * k) = *(const float4*)(src + 4 * k);
        }
        __syncthreads();
#pragma unroll 4
        for (int w = 0; w < 32; ++w) {
            const float4 ra = *(const float4*)(xt + w * 132 + rg * 8);
            const float4 rb = *(const float4*)(xt + w * 132 + rg * 8 + 4);
            const float4 ta = *(const float4*)(twl + w * 132 + vg * 4);
            const float4 tb = *(const float4*)(twl + w * 132 + 64 + vg * 4);
            const float rv[8] = {ra.x, ra.y, ra.z, ra.w, rb.x, rb.y, rb.z, rb.w};
            const float tv[8] = {ta.x, ta.y, ta.z, ta.w, tb.x, tb.y, tb.z, tb.w};
#pragma unroll
            for (int p = 0; p < 8; p++)
#pragma unroll
                for (int q = 0; q < 8; q++) acc[p][q] += rv[p] * tv[q];
        }
    }

    const float sc2 = 2.0f * detal[0];
    float* sp = s + ((size_t)b * CC + c) * NN;
#pragma unroll
    for (int p = 0; p < 8; ++p) {
        const int h = rg * 8 + p;
        float* q0 = sp + (size_t)h * WW + vg * 4;
        float* q1 = sp + (size_t)h * WW + 64 + vg * 4;
        float4 c0 = *(const float4*)q0;
        float4 c1 = *(const float4*)q1;
        c0.x += sc2 * acc[p][0]; c0.y += sc2 * acc[p][1];
        c0.z += sc2 * acc[p][2]; c0.w += sc2 * acc[p][3];
        c1.x += sc2 * acc[p][4]; c1.y += sc2 * acc[p][5];
        c1.z += sc2 * acc[p][6]; c1.w += sc2 * acc[p][7];
        *(float4*)q0 = c0;
        *(float4*)q1 = c1;
    }
}

// ---------------- outconv: out[b,o,n] = sum_c w_out[o,c]*s[b,c,n] + b_out[o] + x[b,o,n] ----------------
// grid (NN/256, 4, NB), block 256. K-chunk-16, DIRECT staging (see k_inconv note:
// persistent-reg prefetch spilled acc to scratch in rounds 4/5).
__global__ __launch_bounds__(256) void k_outconv(
    const float* __restrict__ s, const float* __restrict__ wot,
    const float* __restrict__ b_out, const float* __restrict__ x,
    float* __restrict__ outp)
{
    __shared__ float ss[16 * 260];   // [c][n], stride 260
    __shared__ float wl[16 * 68];    // [c][o_local], stride 68
    const int b  = blockIdx.z;
    const int o0 = blockIdx.y * 64;
    const int n0 = blockIdx.x * 256;
    const int t  = threadIdx.x;
    const int og = t >> 5;           // 0..7
    const int ng = t & 31;

    const int sr = t >> 4, sc = (t & 15) * 4;
    const float* sbase = s + ((size_t)b * CC + sr) * NN + n0 + sc;
    const float* wbase = wot + (size_t)sr * IC + o0 + sc;
    float* sdst = ss + sr * 260 + sc;
    float* wdst = wl + sr * 68 + sc;

    float acc[8][8];
#pragma unroll
    for (int p = 0; p < 8; p++)
#pragma unroll
        for (int q = 0; q < 8; q++) acc[p][q] = 0.f;

    for (int c0 = 0; c0 < CC; c0 += 16) {
        __syncthreads();
        {
            const float* ssrc = sbase + (size_t)c0 * NN;
            const float4 a0 = *(const float4*)(ssrc);
            const float4 a1 = *(const float4*)(ssrc + 64);
            const float4 a2 = *(const float4*)(ssrc + 128);
            const float4 a3 = *(const float4*)(ssrc + 192);
            const float4 w0 = *(const float4*)(wbase + (size_t)c0 * IC);
            *(float4*)(sdst)       = a0;
            *(float4*)(sdst + 64)  = a1;
            *(float4*)(sdst + 128) = a2;
            *(float4*)(sdst + 192) = a3;
            *(float4*)(wdst)       = w0;
        }
        __syncthreads();
#pragma unroll 4
        for (int c = 0; c < 16; ++c) {
            const float4 wa = *(const float4*)(wl + c * 68 + og * 8);
            const float4 wb = *(const float4*)(wl + c * 68 + og * 8 + 4);
            const float4 sa = *(const float4*)(ss + c * 260 + ng * 4);
            const float4 sb = *(const float4*)(ss + c * 260 + 128 + ng * 4);
            const float wv[8] = {wa.x, wa.y, wa.z, wa.w, wb.x, wb.y, wb.z, wb.w};
            const float sv[8] = {sa.x, sa.y, sa.z, sa.w, sb.x, sb.y, sb.z, sb.w};
#pragma unroll
            for (int p = 0; p < 8; p++)
#pragma unroll
                for (int q = 0; q < 8; q++) acc[p][q] += wv[p] * sv[q];
        }
    }

#pragma unroll
    for (int p = 0; p < 8; ++p) {
        const int oo = o0 + og * 8 + p;
        const float bo = b_out[oo];
        const float* xb = x + ((size_t)b * IC + oo) * NN + n0;
        float* ob = outp + ((size_t)b * IC + oo) * NN + n0;
        const float4 x0 = *(const float4*)(xb + ng * 4);
        const float4 x1 = *(const float4*)(xb + 128 + ng * 4);
        *(float4*)(ob + ng * 4) =
            make_float4(acc[p][0] + bo + x0.x, acc[p][1] + bo + x0.y,
                        acc[p][2] + bo + x0.z, acc[p][3] + bo + x0.w);
        *(float4*)(ob + 128 + ng * 4) =
            make_float4(acc[p][4] + bo + x1.x, acc[p][5] + bo + x1.y,
                        acc[p][6] + bo + x1.z, acc[p][7] + bo + x1.w);
    }
}

extern "C" void kernel_launch(void* const* d_in, const int* in_sizes, int n_in,
                              void* d_out, int out_size, void* d_ws, size_t ws_size,
                              hipStream_t stream)
{
    const float* x     = (const float*)d_in[0];
    const float* w_in  = (const float*)d_in[1];
    const float* b_in  = (const float*)d_in[2];
    const float* w_out = (const float*)d_in[3];
    const float* b_out = (const float*)d_in[4];
    const float* detal = (const float*)d_in[5];
    float* out = (float*)d_out;

    float* ws   = (float*)d_ws;
    float* inp  = ws + OFF_INP;
    float* s    = ws + OFF_S;
    float* pW   = ws + OFF_S;      // aliased with s (pW dead before k_co writes s)
    float* pC   = ws + OFF_PC;
    float* Tw   = ws + OFF_TW;
    float* Tc   = ws + OFF_TC;
    float* wt   = ws + OFF_WT;
    float* wot  = ws + OFF_WOT;

    k_wt     <<<dim3(128),              256, 0, stream>>>(w_in, w_out, wt, wot);
    k_inconv <<<dim3(NN / 256, NB),     256, 0, stream>>>(x, wt, b_in, inp);
    k_gramW  <<<dim3(NKW, NB),          256, 0, stream>>>(inp, pW);
    k_redW   <<<dim3(64, NB),           256, 0, stream>>>(pW, Tw);
    k_softW  <<<dim3(NB, 4),           1024, 0, stream>>>(Tw);
    k_gramC  <<<dim3(NKC, NB),          256, 0, stream>>>(inp, pC);
    k_redC   <<<dim3(16, NB),           256, 0, stream>>>(pC, Tc);
    k_softC  <<<dim3(NB),              1024, 0, stream>>>(Tc);
    k_co     <<<dim3(NN / 128, NB),     256, 0, stream>>>(inp, Tc, detal, s);
    k_wo     <<<dim3(CC, NB),           256, 0, stream>>>(inp, Tw, detal, s);
    k_outconv<<<dim3(NN / 256, 4, NB),  256, 0, stream>>>(s, wot, b_out, x, out);
}